// Round 1
// baseline (1402.609 us; speedup 1.0000x reference)
//
#include <hip/hip_runtime.h>

#define NN   50000
#define EE   400000
#define IND  128
#define POSD 64
#define DD   192     // IN + POS
#define EMBD 128
#define LNEPS 1e-5f

// ---------------------------------------------------------------------------
// Kernel 1: edge scatter  agg[dst][0:192] += concat(x,pos)[src]
// 48 threads per edge, 4 dims each (float4 gather, 4 HW f32 atomics)
// ---------------------------------------------------------------------------
__global__ __launch_bounds__(256) void scatter_k(
    const float* __restrict__ x, const float* __restrict__ pos,
    const int* __restrict__ ei, float* __restrict__ agg) {
  int tid = blockIdx.x * 256 + threadIdx.x;
  int e = tid / 48;
  if (e >= EE) return;
  int q = tid - e * 48;
  int src = ei[e];
  int dst = ei[EE + e];
  float4 v;
  if (q < 32) v = *(const float4*)(x   + (size_t)src * IND  + q * 4);
  else        v = *(const float4*)(pos + (size_t)src * POSD + (q - 32) * 4);
  float* a = agg + (size_t)dst * DD + q * 4;
  unsafeAtomicAdd(a + 0, v.x);
  unsafeAtomicAdd(a + 1, v.y);
  unsafeAtomicAdd(a + 2, v.z);
  unsafeAtomicAdd(a + 3, v.w);
}

// ---------------------------------------------------------------------------
// LN (over 128 values held as 2 per lane across a 64-lane wave) + relu
// ---------------------------------------------------------------------------
__device__ inline void ln_relu(float& a0, float& a1, int lane,
                               const float* __restrict__ g,
                               const float* __restrict__ b) {
  float s  = a0 + a1;
  float sq = a0 * a0 + a1 * a1;
#pragma unroll
  for (int off = 1; off < 64; off <<= 1) {
    s  += __shfl_xor(s, off);
    sq += __shfl_xor(sq, off);
  }
  float mean = s * (1.0f / 128.0f);
  float var  = sq * (1.0f / 128.0f) - mean * mean;
  float rstd = rsqrtf(var + LNEPS);
  a0 = fmaxf((a0 - mean) * rstd * g[lane]      + b[lane],      0.0f);
  a1 = fmaxf((a1 - mean) * rstd * g[lane + 64] + b[lane + 64], 0.0f);
}

// ---------------------------------------------------------------------------
// Kernel 2: fused per-node MLP chains (both branches). 1 wave = 1 node.
// ---------------------------------------------------------------------------
__global__ __launch_bounds__(256) void mlp_k(
    const float* __restrict__ x, const float* __restrict__ pos,
    const float* __restrict__ agg,
    const float* __restrict__ epsv,
    const float* __restrict__ W1, const float* __restrict__ b1,
    const float* __restrict__ g1, const float* __restrict__ be1,
    const float* __restrict__ W2, const float* __restrict__ b2,
    const float* __restrict__ lng, const float* __restrict__ lnb,
    const float* __restrict__ epspv,
    const float* __restrict__ W1p, const float* __restrict__ b1p,
    const float* __restrict__ g1p, const float* __restrict__ be1p,
    const float* __restrict__ W2p, const float* __restrict__ b2p,
    const float* __restrict__ lnpg, const float* __restrict__ lnpb,
    float* __restrict__ out) {
  __shared__ float s0[4][DD];
  __shared__ float s1[4][EMBD];
  const int lane = threadIdx.x & 63;
  const int w    = threadIdx.x >> 6;
  const int node = blockIdx.x * 4 + w;   // grid is exact: N % 4 == 0

  const float* ag = agg + (size_t)node * DD;

  // ---- branch h: h0 = (1+eps)*concat(x,pos) + agg  (192 dims, 3/lane) ----
  {
    float e1 = 1.0f + epsv[0];
    float a0 = x[(size_t)node * IND + lane];
    float a1 = x[(size_t)node * IND + lane + 64];
    float a2 = pos[(size_t)node * POSD + lane];
    s0[w][lane]       = fmaf(e1, a0, ag[lane]);
    s0[w][lane + 64]  = fmaf(e1, a1, ag[lane + 64]);
    s0[w][lane + 128] = fmaf(e1, a2, ag[lane + 128]);
  }
  __syncthreads();

  // ---- GEMM1: [192] @ W1[192,128] ----
  float acc0 = b1[lane], acc1 = b1[lane + 64];
#pragma unroll 8
  for (int k = 0; k < DD; ++k) {
    float s = s0[w][k];
    acc0 = fmaf(s, W1[k * EMBD + lane],      acc0);
    acc1 = fmaf(s, W1[k * EMBD + lane + 64], acc1);
  }
  ln_relu(acc0, acc1, lane, g1, be1);
  s1[w][lane] = acc0; s1[w][lane + 64] = acc1;
  __syncthreads();

  // ---- GEMM2: [128] @ W2[128,128] ----
  float c0 = b2[lane], c1 = b2[lane + 64];
#pragma unroll 8
  for (int k = 0; k < EMBD; ++k) {
    float s = s1[w][k];
    c0 = fmaf(s, W2[k * EMBD + lane],      c0);
    c1 = fmaf(s, W2[k * EMBD + lane + 64], c1);
  }
  ln_relu(c0, c1, lane, lng, lnb);
  out[(size_t)node * EMBD + lane]      = c0 + x[(size_t)node * IND + lane];
  out[(size_t)node * EMBD + lane + 64] = c1 + x[(size_t)node * IND + lane + 64];

  // ---- branch p: p0 = (1+epsp)*pos + agg[128:192]  (64 dims, 1/lane) ----
  __syncthreads();
  {
    float ep1 = 1.0f + epspv[0];
    s0[w][lane] = fmaf(ep1, pos[(size_t)node * POSD + lane], ag[128 + lane]);
  }
  __syncthreads();

  // ---- GEMM1p: [64] @ W1p[64,128] ----
  float d0 = b1p[lane], d1 = b1p[lane + 64];
#pragma unroll 8
  for (int k = 0; k < POSD; ++k) {
    float s = s0[w][k];
    d0 = fmaf(s, W1p[k * EMBD + lane],      d0);
    d1 = fmaf(s, W1p[k * EMBD + lane + 64], d1);
  }
  ln_relu(d0, d1, lane, g1p, be1p);
  s1[w][lane] = d0; s1[w][lane + 64] = d1;
  __syncthreads();

  // ---- GEMM2p: [128] @ W2p[128,128] ----
  float f0 = b2p[lane], f1 = b2p[lane + 64];
#pragma unroll 8
  for (int k = 0; k < EMBD; ++k) {
    float s = s1[w][k];
    f0 = fmaf(s, W2p[k * EMBD + lane],      f0);
    f1 = fmaf(s, W2p[k * EMBD + lane + 64], f1);
  }
  ln_relu(f0, f1, lane, lnpg, lnpb);
  out[(size_t)NN * EMBD + (size_t)node * EMBD + lane]      = f0;
  out[(size_t)NN * EMBD + (size_t)node * EMBD + lane + 64] = f1;
}

extern "C" void kernel_launch(void* const* d_in, const int* in_sizes, int n_in,
                              void* d_out, int out_size, void* d_ws, size_t ws_size,
                              hipStream_t stream) {
  const float* x    = (const float*)d_in[0];
  const float* pos  = (const float*)d_in[1];
  const int*   ei   = (const int*)d_in[2];
  const float* eps  = (const float*)d_in[3];
  const float* W1   = (const float*)d_in[4];
  const float* b1   = (const float*)d_in[5];
  const float* g1   = (const float*)d_in[6];
  const float* be1  = (const float*)d_in[7];
  const float* W2   = (const float*)d_in[8];
  const float* b2   = (const float*)d_in[9];
  const float* lng  = (const float*)d_in[10];
  const float* lnb  = (const float*)d_in[11];
  const float* epsp = (const float*)d_in[12];
  const float* W1p  = (const float*)d_in[13];
  const float* b1p  = (const float*)d_in[14];
  const float* g1p  = (const float*)d_in[15];
  const float* be1p = (const float*)d_in[16];
  const float* W2p  = (const float*)d_in[17];
  const float* b2p  = (const float*)d_in[18];
  const float* lnpg = (const float*)d_in[19];
  const float* lnpb = (const float*)d_in[20];

  float* agg = (float*)d_ws;                       // [N][192] f32 = 38.4 MB
  float* out = (float*)d_out;                      // h [N][128] then p [N][128]

  hipMemsetAsync(agg, 0, (size_t)NN * DD * sizeof(float), stream);

  int sc_blocks = (EE * 48) / 256;                 // 75000, exact
  scatter_k<<<sc_blocks, 256, 0, stream>>>(x, pos, ei, agg);

  int mlp_blocks = NN / 4;                         // 12500, exact
  mlp_k<<<mlp_blocks, 256, 0, stream>>>(
      x, pos, agg, eps, W1, b1, g1, be1, W2, b2, lng, lnb,
      epsp, W1p, b1p, g1p, be1p, W2p, b2p, lnpg, lnpb, out);
}

// Round 2
// 253.607 us; speedup vs baseline: 5.5306x; 5.5306x over previous
//
#include <hip/hip_runtime.h>

#define NN   50000
#define EE   400000
#define IND  128
#define POSD 64
#define DD   192     // IN + POS
#define EMBD 128
#define LNEPS 1e-5f
#define CAP  64      // max degree capacity (Poisson(8), max ~22 -> hugely safe)
#define NPW  8       // nodes per wave

// ---------------------------------------------------------------------------
// Kernel 1: bucket fill. 400k int atomics only (no f32 feature atomics).
// ---------------------------------------------------------------------------
__global__ __launch_bounds__(256) void fill_k(
    const int* __restrict__ ei, int* __restrict__ cnt, int* __restrict__ csr) {
  int e = blockIdx.x * 256 + threadIdx.x;
  if (e >= EE) return;
  int src = ei[e];
  int dst = ei[EE + e];
  int idx = atomicAdd(&cnt[dst], 1);
  if (idx < CAP) csr[(size_t)dst * CAP + idx] = src;
}

// ---------------------------------------------------------------------------
// LN over 128 values (2/lane across a 64-lane wave) + relu
// ---------------------------------------------------------------------------
__device__ inline void ln_relu(float& a0, float& a1, int lane,
                               const float* __restrict__ g,
                               const float* __restrict__ b) {
  float s  = a0 + a1;
  float sq = a0 * a0 + a1 * a1;
#pragma unroll
  for (int off = 1; off < 64; off <<= 1) {
    s  += __shfl_xor(s, off);
    sq += __shfl_xor(sq, off);
  }
  float mean = s * (1.0f / 128.0f);
  float var  = sq * (1.0f / 128.0f) - mean * mean;
  float rstd = rsqrtf(var + LNEPS);
  a0 = fmaxf((a0 - mean) * rstd * g[lane]      + b[lane],      0.0f);
  a1 = fmaxf((a1 - mean) * rstd * g[lane + 64] + b[lane + 64], 0.0f);
}

// ---------------------------------------------------------------------------
// Kernel 2: fused gather + both MLP chains.
// Block = 4 waves; each wave owns 8 nodes end-to-end (no __syncthreads).
// Weights loaded from global (L1/L2-cached), reused across the wave's 8 nodes.
// ---------------------------------------------------------------------------
__global__ __launch_bounds__(256) void gmlp_k(
    const float* __restrict__ x, const float* __restrict__ pos,
    const int* __restrict__ cnt, const int* __restrict__ csr,
    const float* __restrict__ epsv,
    const float* __restrict__ W1, const float* __restrict__ b1,
    const float* __restrict__ g1, const float* __restrict__ be1,
    const float* __restrict__ W2, const float* __restrict__ b2,
    const float* __restrict__ lng, const float* __restrict__ lnb,
    const float* __restrict__ epspv,
    const float* __restrict__ W1p, const float* __restrict__ b1p,
    const float* __restrict__ g1p, const float* __restrict__ be1p,
    const float* __restrict__ W2p, const float* __restrict__ b2p,
    const float* __restrict__ lnpg, const float* __restrict__ lnpb,
    float* __restrict__ out) {
  __shared__ float s0[32][DD];    // 24 KB  h-branch input (per-wave private)
  __shared__ float p0[32][POSD];  //  8 KB  p-branch input
  __shared__ float s1[32][EMBD];  // 16 KB  hidden
  const int lane = threadIdx.x & 63;
  const int w    = threadIdx.x >> 6;
  const int nb   = w * NPW;                   // node slot base within block
  const int node0 = blockIdx.x * 32 + nb;     // NN % 8 == 0, so waves are full
  if (node0 >= NN) return;

  const float e1  = 1.0f + epsv[0];
  const float ep1 = 1.0f + epspv[0];

  // ---- gather: agg over CSR bucket, then h0 / p0 into LDS ----
  for (int j = 0; j < NPW; ++j) {
    const int n = node0 + j;
    float a0 = 0.f, a1 = 0.f, a2 = 0.f;
    int deg = cnt[n]; if (deg > CAP) deg = CAP;
    const int* row = csr + (size_t)n * CAP;
    for (int t = 0; t < deg; ++t) {
      int s = row[t];   // wave-uniform -> scalar load
      a0 += x[(size_t)s * IND + lane];
      a1 += x[(size_t)s * IND + 64 + lane];
      a2 += pos[(size_t)s * POSD + lane];
    }
    float xs0 = x[(size_t)n * IND + lane];
    float xs1 = x[(size_t)n * IND + 64 + lane];
    float ps  = pos[(size_t)n * POSD + lane];
    s0[nb + j][lane]       = fmaf(e1, xs0, a0);
    s0[nb + j][64 + lane]  = fmaf(e1, xs1, a1);
    s0[nb + j][128 + lane] = fmaf(e1, ps,  a2);
    p0[nb + j][lane]       = fmaf(ep1, ps, a2);
  }

  float c0[NPW], c1[NPW];

  // ---- GEMM1 (h): [192] @ W1[192,128], 8-node weight reuse ----
#pragma unroll
  for (int j = 0; j < NPW; ++j) { c0[j] = b1[lane]; c1[j] = b1[64 + lane]; }
  for (int k = 0; k < DD; k += 4) {
    float w00 = W1[(k + 0) * EMBD + lane],      w01 = W1[(k + 1) * EMBD + lane];
    float w02 = W1[(k + 2) * EMBD + lane],      w03 = W1[(k + 3) * EMBD + lane];
    float w10 = W1[(k + 0) * EMBD + 64 + lane], w11 = W1[(k + 1) * EMBD + 64 + lane];
    float w12 = W1[(k + 2) * EMBD + 64 + lane], w13 = W1[(k + 3) * EMBD + 64 + lane];
#pragma unroll
    for (int j = 0; j < NPW; ++j) {
      float4 s = *(const float4*)&s0[nb + j][k];   // broadcast b128
      c0[j] = fmaf(s.x, w00, c0[j]); c0[j] = fmaf(s.y, w01, c0[j]);
      c0[j] = fmaf(s.z, w02, c0[j]); c0[j] = fmaf(s.w, w03, c0[j]);
      c1[j] = fmaf(s.x, w10, c1[j]); c1[j] = fmaf(s.y, w11, c1[j]);
      c1[j] = fmaf(s.z, w12, c1[j]); c1[j] = fmaf(s.w, w13, c1[j]);
    }
  }
#pragma unroll
  for (int j = 0; j < NPW; ++j) {
    ln_relu(c0[j], c1[j], lane, g1, be1);
    s1[nb + j][lane] = c0[j]; s1[nb + j][64 + lane] = c1[j];
  }

  // ---- GEMM2 (h): [128] @ W2[128,128] -> LN -> relu -> +x ----
#pragma unroll
  for (int j = 0; j < NPW; ++j) { c0[j] = b2[lane]; c1[j] = b2[64 + lane]; }
  for (int k = 0; k < EMBD; k += 4) {
    float w00 = W2[(k + 0) * EMBD + lane],      w01 = W2[(k + 1) * EMBD + lane];
    float w02 = W2[(k + 2) * EMBD + lane],      w03 = W2[(k + 3) * EMBD + lane];
    float w10 = W2[(k + 0) * EMBD + 64 + lane], w11 = W2[(k + 1) * EMBD + 64 + lane];
    float w12 = W2[(k + 2) * EMBD + 64 + lane], w13 = W2[(k + 3) * EMBD + 64 + lane];
#pragma unroll
    for (int j = 0; j < NPW; ++j) {
      float4 s = *(const float4*)&s1[nb + j][k];
      c0[j] = fmaf(s.x, w00, c0[j]); c0[j] = fmaf(s.y, w01, c0[j]);
      c0[j] = fmaf(s.z, w02, c0[j]); c0[j] = fmaf(s.w, w03, c0[j]);
      c1[j] = fmaf(s.x, w10, c1[j]); c1[j] = fmaf(s.y, w11, c1[j]);
      c1[j] = fmaf(s.z, w12, c1[j]); c1[j] = fmaf(s.w, w13, c1[j]);
    }
  }
#pragma unroll
  for (int j = 0; j < NPW; ++j) {
    const int n = node0 + j;
    ln_relu(c0[j], c1[j], lane, lng, lnb);
    out[(size_t)n * EMBD + lane]      = c0[j] + x[(size_t)n * IND + lane];
    out[(size_t)n * EMBD + 64 + lane] = c1[j] + x[(size_t)n * IND + 64 + lane];
  }

  // ---- GEMM1p: [64] @ W1p[64,128] ----
#pragma unroll
  for (int j = 0; j < NPW; ++j) { c0[j] = b1p[lane]; c1[j] = b1p[64 + lane]; }
  for (int k = 0; k < POSD; k += 4) {
    float w00 = W1p[(k + 0) * EMBD + lane],      w01 = W1p[(k + 1) * EMBD + lane];
    float w02 = W1p[(k + 2) * EMBD + lane],      w03 = W1p[(k + 3) * EMBD + lane];
    float w10 = W1p[(k + 0) * EMBD + 64 + lane], w11 = W1p[(k + 1) * EMBD + 64 + lane];
    float w12 = W1p[(k + 2) * EMBD + 64 + lane], w13 = W1p[(k + 3) * EMBD + 64 + lane];
#pragma unroll
    for (int j = 0; j < NPW; ++j) {
      float4 s = *(const float4*)&p0[nb + j][k];
      c0[j] = fmaf(s.x, w00, c0[j]); c0[j] = fmaf(s.y, w01, c0[j]);
      c0[j] = fmaf(s.z, w02, c0[j]); c0[j] = fmaf(s.w, w03, c0[j]);
      c1[j] = fmaf(s.x, w10, c1[j]); c1[j] = fmaf(s.y, w11, c1[j]);
      c1[j] = fmaf(s.z, w12, c1[j]); c1[j] = fmaf(s.w, w13, c1[j]);
    }
  }
#pragma unroll
  for (int j = 0; j < NPW; ++j) {
    ln_relu(c0[j], c1[j], lane, g1p, be1p);
    s1[nb + j][lane] = c0[j]; s1[nb + j][64 + lane] = c1[j];
  }

  // ---- GEMM2p: [128] @ W2p[128,128] -> LN -> relu ----
#pragma unroll
  for (int j = 0; j < NPW; ++j) { c0[j] = b2p[lane]; c1[j] = b2p[64 + lane]; }
  for (int k = 0; k < EMBD; k += 4) {
    float w00 = W2p[(k + 0) * EMBD + lane],      w01 = W2p[(k + 1) * EMBD + lane];
    float w02 = W2p[(k + 2) * EMBD + lane],      w03 = W2p[(k + 3) * EMBD + lane];
    float w10 = W2p[(k + 0) * EMBD + 64 + lane], w11 = W2p[(k + 1) * EMBD + 64 + lane];
    float w12 = W2p[(k + 2) * EMBD + 64 + lane], w13 = W2p[(k + 3) * EMBD + 64 + lane];
#pragma unroll
    for (int j = 0; j < NPW; ++j) {
      float4 s = *(const float4*)&s1[nb + j][k];
      c0[j] = fmaf(s.x, w00, c0[j]); c0[j] = fmaf(s.y, w01, c0[j]);
      c0[j] = fmaf(s.z, w02, c0[j]); c0[j] = fmaf(s.w, w03, c0[j]);
      c1[j] = fmaf(s.x, w10, c1[j]); c1[j] = fmaf(s.y, w11, c1[j]);
      c1[j] = fmaf(s.z, w12, c1[j]); c1[j] = fmaf(s.w, w13, c1[j]);
    }
  }
#pragma unroll
  for (int j = 0; j < NPW; ++j) {
    const int n = node0 + j;
    ln_relu(c0[j], c1[j], lane, lnpg, lnpb);
    out[(size_t)NN * EMBD + (size_t)n * EMBD + lane]      = c0[j];
    out[(size_t)NN * EMBD + (size_t)n * EMBD + 64 + lane] = c1[j];
  }
}

extern "C" void kernel_launch(void* const* d_in, const int* in_sizes, int n_in,
                              void* d_out, int out_size, void* d_ws, size_t ws_size,
                              hipStream_t stream) {
  const float* x    = (const float*)d_in[0];
  const float* pos  = (const float*)d_in[1];
  const int*   ei   = (const int*)d_in[2];
  const float* eps  = (const float*)d_in[3];
  const float* W1   = (const float*)d_in[4];
  const float* b1   = (const float*)d_in[5];
  const float* g1   = (const float*)d_in[6];
  const float* be1  = (const float*)d_in[7];
  const float* W2   = (const float*)d_in[8];
  const float* b2   = (const float*)d_in[9];
  const float* lng  = (const float*)d_in[10];
  const float* lnb  = (const float*)d_in[11];
  const float* epsp = (const float*)d_in[12];
  const float* W1p  = (const float*)d_in[13];
  const float* b1p  = (const float*)d_in[14];
  const float* g1p  = (const float*)d_in[15];
  const float* be1p = (const float*)d_in[16];
  const float* W2p  = (const float*)d_in[17];
  const float* b2p  = (const float*)d_in[18];
  const float* lnpg = (const float*)d_in[19];
  const float* lnpb = (const float*)d_in[20];

  int* cnt = (int*)d_ws;                                   // [NN]      200 KB
  int* csr = (int*)((char*)d_ws + (size_t)NN * sizeof(int)); // [NN][CAP] 12.8 MB
  float* out = (float*)d_out;

  hipMemsetAsync(cnt, 0, (size_t)NN * sizeof(int), stream);

  fill_k<<<(EE + 255) / 256, 256, 0, stream>>>(ei, cnt, csr);

  int blocks = (NN + 31) / 32;   // 1563
  gmlp_k<<<blocks, 256, 0, stream>>>(
      x, pos, cnt, csr, eps, W1, b1, g1, be1, W2, b2, lng, lnb,
      epsp, W1p, b1p, g1p, be1p, W2p, b2p, lnpg, lnpb, out);
}

// Round 3
// 172.320 us; speedup vs baseline: 8.1396x; 1.4717x over previous
//
#include <hip/hip_runtime.h>

#define NN    50000
#define NPAD  50048       // 391 blocks * 128
#define EE    400000
#define IND   128
#define POSD  64
#define DD    192
#define EMBD  128
#define LNEPS 1e-5f
#define CAP   32

typedef __attribute__((ext_vector_type(8))) short bf16x8;
typedef __attribute__((ext_vector_type(4))) float f32x4;
typedef unsigned short ushort_t;

#define MFMA16 __builtin_amdgcn_mfma_f32_16x16x32_bf16

__device__ inline ushort_t f2bf(float f) {
  union { float f; unsigned u; } v; v.f = f;
  unsigned r = (v.u + 0x7FFFu + ((v.u >> 16) & 1u)) >> 16;
  return (ushort_t)r;
}

// ---------------------------------------------------------------------------
// Kernel 1: CSR bucket fill (int atomics only)
// ---------------------------------------------------------------------------
__global__ __launch_bounds__(256) void fill_k(
    const int* __restrict__ ei, int* __restrict__ cnt, int* __restrict__ csr) {
  int e = blockIdx.x * 256 + threadIdx.x;
  if (e >= EE) return;
  int src = ei[e];
  int dst = ei[EE + e];
  int idx = atomicAdd(&cnt[dst], 1);
  if (idx < CAP) csr[(size_t)dst * CAP + idx] = src;
}

// ---------------------------------------------------------------------------
// Kernel 2: weights -> bf16, transposed to [col][k] for contiguous B-frags
// regions in wt: W1t 128*192 | W2t 128*128 | W1pt 128*64 | W2pt 128*128
// ---------------------------------------------------------------------------
__global__ __launch_bounds__(256) void wconv_k(
    const float* __restrict__ W1, const float* __restrict__ W2,
    const float* __restrict__ W1p, const float* __restrict__ W2p,
    ushort_t* __restrict__ wt) {
  int tid = blockIdx.x * 256 + threadIdx.x;   // 65536 total
  if (tid < 24576) {                                   // W1t [128][192]
    int c = tid / 192, k = tid % 192;
    wt[tid] = f2bf(W1[k * EMBD + c]);
  } else if (tid < 24576 + 16384) {                    // W2t [128][128]
    int t = tid - 24576; int c = t / 128, k = t % 128;
    wt[tid] = f2bf(W2[k * EMBD + c]);
  } else if (tid < 24576 + 16384 + 8192) {             // W1pt [128][64]
    int t = tid - 24576 - 16384; int c = t / 64, k = t % 64;
    wt[tid] = f2bf(W1p[k * EMBD + c]);
  } else {                                             // W2pt [128][128]
    int t = tid - 24576 - 16384 - 8192; int c = t / 128, k = t % 128;
    wt[tid] = f2bf(W2p[k * EMBD + c]);
  }
}

// ---------------------------------------------------------------------------
// Kernel 3: gather. One wave per node; neighbor idx loaded once (coalesced),
// broadcast via shfl. Writes h0 [N][192] bf16 and p0 [N][64] bf16.
// ---------------------------------------------------------------------------
__global__ __launch_bounds__(256) void gather_k(
    const float* __restrict__ x, const float* __restrict__ pos,
    const int* __restrict__ cnt, const int* __restrict__ csr,
    const float* __restrict__ epsv, const float* __restrict__ epspv,
    ushort_t* __restrict__ h0, ushort_t* __restrict__ p0) {
  const int lane = threadIdx.x & 63;
  const int wv   = threadIdx.x >> 6;
  const int n    = blockIdx.x * 4 + wv;
  if (n >= NN) return;

  int deg = cnt[n]; if (deg > CAP) deg = CAP;
  const int* row = csr + (size_t)n * CAP;
  int idx = (lane < deg) ? row[lane] : 0;

  float a0 = 0.f, a1 = 0.f, a2 = 0.f;
  int t = 0;
  for (; t + 2 <= deg; t += 2) {
    int s1 = __shfl(idx, t);
    int s2 = __shfl(idx, t + 1);
    float u0 = x[(size_t)s1 * IND + lane];
    float u1 = x[(size_t)s1 * IND + 64 + lane];
    float u2 = pos[(size_t)s1 * POSD + lane];
    float v0 = x[(size_t)s2 * IND + lane];
    float v1 = x[(size_t)s2 * IND + 64 + lane];
    float v2 = pos[(size_t)s2 * POSD + lane];
    a0 += u0 + v0; a1 += u1 + v1; a2 += u2 + v2;
  }
  if (t < deg) {
    int s1 = __shfl(idx, t);
    a0 += x[(size_t)s1 * IND + lane];
    a1 += x[(size_t)s1 * IND + 64 + lane];
    a2 += pos[(size_t)s1 * POSD + lane];
  }

  float e1  = 1.0f + epsv[0];
  float ep1 = 1.0f + epspv[0];
  float xs0 = x[(size_t)n * IND + lane];
  float xs1 = x[(size_t)n * IND + 64 + lane];
  float ps  = pos[(size_t)n * POSD + lane];

  h0[(size_t)n * DD + lane]       = f2bf(fmaf(e1, xs0, a0));
  h0[(size_t)n * DD + 64 + lane]  = f2bf(fmaf(e1, xs1, a1));
  h0[(size_t)n * DD + 128 + lane] = f2bf(fmaf(e1, ps,  a2));
  p0[(size_t)n * POSD + lane]     = f2bf(fmaf(ep1, ps, a2));
}

// ---------------------------------------------------------------------------
// LN+bias+relu epilogue on the 2x8 f32x4 accumulator block.
// C layout per 16x16 tile: col = lane&15, row = (lane>>4)*4 + reg.
// Row r of the wave lives entirely in the 16 lanes of group g=(r%16)/4.
// ---------------------------------------------------------------------------
__device__ inline void ln_epi(f32x4 (&acc)[2][8],
                              const float* __restrict__ bias,
                              const float* __restrict__ gam,
                              const float* __restrict__ bet, int c0) {
  float bv[8], gv[8], bev[8];
#pragma unroll
  for (int nt = 0; nt < 8; ++nt) {
    bv[nt]  = bias[nt * 16 + c0];
    gv[nt]  = gam[nt * 16 + c0];
    bev[nt] = bet[nt * 16 + c0];
  }
#pragma unroll
  for (int mt = 0; mt < 2; ++mt) {
#pragma unroll
    for (int r = 0; r < 4; ++r) {
      float s = 0.f, sq = 0.f;
#pragma unroll
      for (int nt = 0; nt < 8; ++nt) {
        float v = acc[mt][nt][r] + bv[nt];
        acc[mt][nt][r] = v;
        s += v; sq += v * v;
      }
#pragma unroll
      for (int off = 1; off < 16; off <<= 1) {
        s  += __shfl_xor(s, off);
        sq += __shfl_xor(sq, off);
      }
      float mean = s * (1.0f / 128.0f);
      float var  = sq * (1.0f / 128.0f) - mean * mean;
      float rstd = rsqrtf(var + LNEPS);
#pragma unroll
      for (int nt = 0; nt < 8; ++nt) {
        acc[mt][nt][r] =
            fmaxf(fmaf((acc[mt][nt][r] - mean) * rstd, gv[nt], bev[nt]), 0.f);
      }
    }
  }
}

// write acc (post-LN) as bf16 into LDS [128][128] with XOR swizzle
__device__ inline void lds_write_acc(ushort_t* lds, f32x4 (&acc)[2][8],
                                     int rb, int g, int c0) {
#pragma unroll
  for (int mt = 0; mt < 2; ++mt)
#pragma unroll
    for (int nt = 0; nt < 8; ++nt)
#pragma unroll
      for (int r = 0; r < 4; ++r) {
        int row  = rb + mt * 16 + g * 4 + r;
        int byte = row * 256 + (((nt * 16 + c0) * 2) ^ ((row & 7) << 4));
        *(ushort_t*)((char*)lds + byte) = f2bf(acc[mt][nt][r]);
      }
}

// ---------------------------------------------------------------------------
// Kernel 4: MFMA MLP. Block = 256 thr (4 waves), M-tile = 128 nodes.
// Wave tile = 32 rows x 128 cols (M_rep=2, N_rep=8, 16x16x32 bf16).
// ---------------------------------------------------------------------------
__global__ __launch_bounds__(256) void mlp_k(
    const ushort_t* __restrict__ h0, const ushort_t* __restrict__ p0,
    const ushort_t* __restrict__ wt,
    const float* __restrict__ b1, const float* __restrict__ g1,
    const float* __restrict__ be1,
    const float* __restrict__ b2, const float* __restrict__ lng,
    const float* __restrict__ lnb,
    const float* __restrict__ b1p, const float* __restrict__ g1p,
    const float* __restrict__ be1p,
    const float* __restrict__ b2p, const float* __restrict__ lnpg,
    const float* __restrict__ lnpb,
    const float* __restrict__ x, float* __restrict__ out) {
  __shared__ ushort_t lds[128 * 128];   // 32 KB
  const int lane = threadIdx.x & 63;
  const int wv   = threadIdx.x >> 6;
  const int g    = lane >> 4;
  const int c0   = lane & 15;
  const int rb   = wv * 32;
  const int m0   = blockIdx.x * 128;

  const ushort_t* W1t  = wt;
  const ushort_t* W2t  = wt + 24576;
  const ushort_t* W1pt = wt + 24576 + 16384;
  const ushort_t* W2pt = wt + 24576 + 16384 + 8192;

  f32x4 acc[2][8];

  // ================= GEMM1: h0[.,192] @ W1 =================
#pragma unroll
  for (int mt = 0; mt < 2; ++mt)
#pragma unroll
    for (int nt = 0; nt < 8; ++nt) acc[mt][nt] = (f32x4){0.f, 0.f, 0.f, 0.f};

#pragma unroll
  for (int ks = 0; ks < 6; ++ks) {
    bf16x8 a0 = *(const bf16x8*)(h0 + (size_t)(m0 + rb + c0) * DD + ks * 32 + g * 8);
    bf16x8 a1 = *(const bf16x8*)(h0 + (size_t)(m0 + rb + 16 + c0) * DD + ks * 32 + g * 8);
#pragma unroll
    for (int nt = 0; nt < 8; ++nt) {
      bf16x8 b = *(const bf16x8*)(W1t + (nt * 16 + c0) * DD + ks * 32 + g * 8);
      acc[0][nt] = MFMA16(a0, b, acc[0][nt], 0, 0, 0);
      acc[1][nt] = MFMA16(a1, b, acc[1][nt], 0, 0, 0);
    }
  }
  ln_epi(acc, b1, g1, be1, c0);
  lds_write_acc(lds, acc, rb, g, c0);
  __syncthreads();

  // ================= GEMM2: h1 @ W2, +residual =================
#pragma unroll
  for (int mt = 0; mt < 2; ++mt)
#pragma unroll
    for (int nt = 0; nt < 8; ++nt) acc[mt][nt] = (f32x4){0.f, 0.f, 0.f, 0.f};

#pragma unroll
  for (int ks = 0; ks < 4; ++ks) {
#pragma unroll
    for (int mt = 0; mt < 2; ++mt) {
      int row  = rb + mt * 16 + c0;
      int byte = row * 256 + (((ks * 32 + g * 8) * 2) ^ ((row & 7) << 4));
      bf16x8 a = *(const bf16x8*)((const char*)lds + byte);
#pragma unroll
      for (int nt = 0; nt < 8; ++nt) {
        bf16x8 b = *(const bf16x8*)(W2t + (nt * 16 + c0) * EMBD + ks * 32 + g * 8);
        acc[mt][nt] = MFMA16(a, b, acc[mt][nt], 0, 0, 0);
      }
    }
  }
  ln_epi(acc, b2, lng, lnb, c0);
#pragma unroll
  for (int mt = 0; mt < 2; ++mt)
#pragma unroll
    for (int nt = 0; nt < 8; ++nt)
#pragma unroll
      for (int r = 0; r < 4; ++r) {
        int row  = rb + mt * 16 + g * 4 + r;
        int node = m0 + row;
        int col  = nt * 16 + c0;
        if (node < NN)
          out[(size_t)node * EMBD + col] =
              acc[mt][nt][r] + x[(size_t)node * IND + col];
      }

  // ================= GEMM1p: p0[.,64] @ W1p =================
#pragma unroll
  for (int mt = 0; mt < 2; ++mt)
#pragma unroll
    for (int nt = 0; nt < 8; ++nt) acc[mt][nt] = (f32x4){0.f, 0.f, 0.f, 0.f};

#pragma unroll
  for (int ks = 0; ks < 2; ++ks) {
    bf16x8 a0 = *(const bf16x8*)(p0 + (size_t)(m0 + rb + c0) * POSD + ks * 32 + g * 8);
    bf16x8 a1 = *(const bf16x8*)(p0 + (size_t)(m0 + rb + 16 + c0) * POSD + ks * 32 + g * 8);
#pragma unroll
    for (int nt = 0; nt < 8; ++nt) {
      bf16x8 b = *(const bf16x8*)(W1pt + (nt * 16 + c0) * POSD + ks * 32 + g * 8);
      acc[0][nt] = MFMA16(a0, b, acc[0][nt], 0, 0, 0);
      acc[1][nt] = MFMA16(a1, b, acc[1][nt], 0, 0, 0);
    }
  }
  ln_epi(acc, b1p, g1p, be1p, c0);
  __syncthreads();                 // all GEMM2 LDS reads done
  lds_write_acc(lds, acc, rb, g, c0);
  __syncthreads();

  // ================= GEMM2p: p1 @ W2p =================
#pragma unroll
  for (int mt = 0; mt < 2; ++mt)
#pragma unroll
    for (int nt = 0; nt < 8; ++nt) acc[mt][nt] = (f32x4){0.f, 0.f, 0.f, 0.f};

#pragma unroll
  for (int ks = 0; ks < 4; ++ks) {
#pragma unroll
    for (int mt = 0; mt < 2; ++mt) {
      int row  = rb + mt * 16 + c0;
      int byte = row * 256 + (((ks * 32 + g * 8) * 2) ^ ((row & 7) << 4));
      bf16x8 a = *(const bf16x8*)((const char*)lds + byte);
#pragma unroll
      for (int nt = 0; nt < 8; ++nt) {
        bf16x8 b = *(const bf16x8*)(W2pt + (nt * 16 + c0) * EMBD + ks * 32 + g * 8);
        acc[mt][nt] = MFMA16(a, b, acc[mt][nt], 0, 0, 0);
      }
    }
  }
  ln_epi(acc, b2p, lnpg, lnpb, c0);
#pragma unroll
  for (int mt = 0; mt < 2; ++mt)
#pragma unroll
    for (int nt = 0; nt < 8; ++nt)
#pragma unroll
      for (int r = 0; r < 4; ++r) {
        int row  = rb + mt * 16 + g * 4 + r;
        int node = m0 + row;
        int col  = nt * 16 + c0;
        if (node < NN)
          out[(size_t)NN * EMBD + (size_t)node * EMBD + col] = acc[mt][nt][r];
      }
}

extern "C" void kernel_launch(void* const* d_in, const int* in_sizes, int n_in,
                              void* d_out, int out_size, void* d_ws, size_t ws_size,
                              hipStream_t stream) {
  const float* x    = (const float*)d_in[0];
  const float* pos  = (const float*)d_in[1];
  const int*   ei   = (const int*)d_in[2];
  const float* eps  = (const float*)d_in[3];
  const float* W1   = (const float*)d_in[4];
  const float* b1   = (const float*)d_in[5];
  const float* g1   = (const float*)d_in[6];
  const float* be1  = (const float*)d_in[7];
  const float* W2   = (const float*)d_in[8];
  const float* b2   = (const float*)d_in[9];
  const float* lng  = (const float*)d_in[10];
  const float* lnb  = (const float*)d_in[11];
  const float* epsp = (const float*)d_in[12];
  const float* W1p  = (const float*)d_in[13];
  const float* b1p  = (const float*)d_in[14];
  const float* g1p  = (const float*)d_in[15];
  const float* be1p = (const float*)d_in[16];
  const float* W2p  = (const float*)d_in[17];
  const float* b2p  = (const float*)d_in[18];
  const float* lnpg = (const float*)d_in[19];
  const float* lnpb = (const float*)d_in[20];

  char* ws = (char*)d_ws;
  int*      cnt = (int*)ws;                                  // 200,000 B
  int*      csr = (int*)(ws + 200000);                       // 6,400,000 B
  ushort_t* h0  = (ushort_t*)(ws + 6600000);                 // 50048*192*2
  ushort_t* p0  = (ushort_t*)(ws + 25818432);                // 50048*64*2
  ushort_t* wt  = (ushort_t*)(ws + 32224576);                // 131,072 B
  float*    out = (float*)d_out;

  hipMemsetAsync(cnt, 0, (size_t)NN * sizeof(int), stream);
  fill_k<<<(EE + 255) / 256, 256, 0, stream>>>(ei, cnt, csr);
  wconv_k<<<256, 256, 0, stream>>>(W1, W2, W1p, W2p, wt);
  gather_k<<<(NN + 3) / 4, 256, 0, stream>>>(x, pos, cnt, csr, eps, epsp, h0, p0);
  mlp_k<<<NPAD / 128, 256, 0, stream>>>(
      h0, p0, wt, b1, g1, be1, b2, lng, lnb,
      b1p, g1p, be1p, b2p, lnpg, lnpb, x, out);
}

// Round 4
// 153.542 us; speedup vs baseline: 9.1350x; 1.1223x over previous
//
#include <hip/hip_runtime.h>

#define NN    50000
#define NPAD  50048       // 782 * 64
#define HB    782         // h-branch blocks (64 rows each)
#define EE    400000
#define IND   128
#define POSD  64
#define DD    192
#define EMBD  128
#define LNEPS 1e-5f
#define CAP   32

typedef __attribute__((ext_vector_type(8))) short bf16x8;
typedef __attribute__((ext_vector_type(4))) float f32x4;
typedef unsigned short ushort_t;

#define MFMA16 __builtin_amdgcn_mfma_f32_16x16x32_bf16

__device__ inline ushort_t f2bf(float f) {
  union { float f; unsigned u; } v; v.f = f;
  unsigned r = (v.u + 0x7FFFu + ((v.u >> 16) & 1u)) >> 16;
  return (ushort_t)r;
}

// ---------------------------------------------------------------------------
// Kernel 1: CSR bucket fill (int atomics only)
// ---------------------------------------------------------------------------
__global__ __launch_bounds__(256) void fill_k(
    const int* __restrict__ ei, int* __restrict__ cnt, int* __restrict__ csr) {
  int e = blockIdx.x * 256 + threadIdx.x;
  if (e >= EE) return;
  int src = ei[e];
  int dst = ei[EE + e];
  int idx = atomicAdd(&cnt[dst], 1);
  if (idx < CAP) csr[(size_t)dst * CAP + idx] = src;
}

// ---------------------------------------------------------------------------
// Kernel 2: weights -> bf16, transposed to [col][k]
// wt: W1t [128][192] | W2t [128][128] | W1pt [128][64] | W2pt [128][128]
// ---------------------------------------------------------------------------
__global__ __launch_bounds__(256) void wconv_k(
    const float* __restrict__ W1, const float* __restrict__ W2,
    const float* __restrict__ W1p, const float* __restrict__ W2p,
    ushort_t* __restrict__ wt) {
  int tid = blockIdx.x * 256 + threadIdx.x;   // 65536 total
  if (tid < 24576) {                                   // W1t
    int c = tid / 192, k = tid % 192;
    wt[tid] = f2bf(W1[k * EMBD + c]);
  } else if (tid < 24576 + 16384) {                    // W2t
    int t = tid - 24576; int c = t / 128, k = t % 128;
    wt[tid] = f2bf(W2[k * EMBD + c]);
  } else if (tid < 24576 + 16384 + 8192) {             // W1pt
    int t = tid - 24576 - 16384; int c = t / 64, k = t % 64;
    wt[tid] = f2bf(W1p[k * EMBD + c]);
  } else {                                             // W2pt
    int t = tid - 24576 - 16384 - 8192; int c = t / 128, k = t % 128;
    wt[tid] = f2bf(W2p[k * EMBD + c]);
  }
}

// ---------------------------------------------------------------------------
// Kernel 3: gather. One wave per node; covers NPAD (pad rows -> zeros).
// ---------------------------------------------------------------------------
__global__ __launch_bounds__(256) void gather_k(
    const float* __restrict__ x, const float* __restrict__ pos,
    const int* __restrict__ cnt, const int* __restrict__ csr,
    const float* __restrict__ epsv, const float* __restrict__ epspv,
    ushort_t* __restrict__ h0, ushort_t* __restrict__ p0) {
  const int lane = threadIdx.x & 63;
  const int wv   = threadIdx.x >> 6;
  const int n    = blockIdx.x * 4 + wv;
  if (n >= NPAD) return;

  float a0 = 0.f, a1 = 0.f, a2 = 0.f;
  float xs0 = 0.f, xs1 = 0.f, ps = 0.f;

  if (n < NN) {
    int deg = cnt[n]; if (deg > CAP) deg = CAP;
    const int* row = csr + (size_t)n * CAP;
    int idx = (lane < deg) ? row[lane] : 0;
    int t = 0;
    for (; t + 2 <= deg; t += 2) {
      int s1 = __shfl(idx, t);
      int s2 = __shfl(idx, t + 1);
      float u0 = x[(size_t)s1 * IND + lane];
      float u1 = x[(size_t)s1 * IND + 64 + lane];
      float u2 = pos[(size_t)s1 * POSD + lane];
      float v0 = x[(size_t)s2 * IND + lane];
      float v1 = x[(size_t)s2 * IND + 64 + lane];
      float v2 = pos[(size_t)s2 * POSD + lane];
      a0 += u0 + v0; a1 += u1 + v1; a2 += u2 + v2;
    }
    if (t < deg) {
      int s1 = __shfl(idx, t);
      a0 += x[(size_t)s1 * IND + lane];
      a1 += x[(size_t)s1 * IND + 64 + lane];
      a2 += pos[(size_t)s1 * POSD + lane];
    }
    xs0 = x[(size_t)n * IND + lane];
    xs1 = x[(size_t)n * IND + 64 + lane];
    ps  = pos[(size_t)n * POSD + lane];
  }

  float e1  = 1.0f + epsv[0];
  float ep1 = 1.0f + epspv[0];
  h0[(size_t)n * DD + lane]       = f2bf(fmaf(e1, xs0, a0));
  h0[(size_t)n * DD + 64 + lane]  = f2bf(fmaf(e1, xs1, a1));
  h0[(size_t)n * DD + 128 + lane] = f2bf(fmaf(e1, ps,  a2));
  p0[(size_t)n * POSD + lane]     = f2bf(fmaf(ep1, ps, a2));
}

// ---------------------------------------------------------------------------
// LN+bias+relu on 2x8 f32x4 acc. C layout: col=lane&15, row=(lane>>4)*4+reg.
// ---------------------------------------------------------------------------
__device__ inline void ln_epi(f32x4 (&acc)[2][8],
                              const float* __restrict__ bias,
                              const float* __restrict__ gam,
                              const float* __restrict__ bet, int c0) {
  float bv[8], gv[8], bev[8];
#pragma unroll
  for (int nt = 0; nt < 8; ++nt) {
    bv[nt]  = bias[nt * 16 + c0];
    gv[nt]  = gam[nt * 16 + c0];
    bev[nt] = bet[nt * 16 + c0];
  }
#pragma unroll
  for (int mt = 0; mt < 2; ++mt) {
#pragma unroll
    for (int r = 0; r < 4; ++r) {
      float s = 0.f, sq = 0.f;
#pragma unroll
      for (int nt = 0; nt < 8; ++nt) {
        float v = acc[mt][nt][r] + bv[nt];
        acc[mt][nt][r] = v;
        s += v; sq += v * v;
      }
#pragma unroll
      for (int off = 1; off < 16; off <<= 1) {
        s  += __shfl_xor(s, off);
        sq += __shfl_xor(sq, off);
      }
      float mean = s * (1.0f / 128.0f);
      float var  = sq * (1.0f / 128.0f) - mean * mean;
      float rstd = rsqrtf(var + LNEPS);
#pragma unroll
      for (int nt = 0; nt < 8; ++nt) {
        acc[mt][nt][r] =
            fmaxf(fmaf((acc[mt][nt][r] - mean) * rstd, gv[nt], bev[nt]), 0.f);
      }
    }
  }
}

// write acc (post-LN) as bf16 into wave-private LDS slab, XOR-swizzled
__device__ inline void lds_write_acc(ushort_t* lds, f32x4 (&acc)[2][8],
                                     int rb, int g, int c0) {
#pragma unroll
  for (int mt = 0; mt < 2; ++mt)
#pragma unroll
    for (int nt = 0; nt < 8; ++nt)
#pragma unroll
      for (int r = 0; r < 4; ++r) {
        int lr   = rb + mt * 16 + g * 4 + r;
        int byte = lr * 256 + (((nt * 16 + c0) * 2) ^ ((lr & 7) << 4));
        *(ushort_t*)((char*)lds + byte) = f2bf(acc[mt][nt][r]);
      }
}

// ---------------------------------------------------------------------------
// Kernel 4: MFMA MLP. 128 threads (2 waves), 64 rows/block.
// Blocks [0,HB): h-branch; [HB,2*HB): p-branch. No __syncthreads (wave-
// private LDS slabs).
// ---------------------------------------------------------------------------
__global__ __launch_bounds__(128) void mlp_k(
    const ushort_t* __restrict__ h0, const ushort_t* __restrict__ p0,
    const ushort_t* __restrict__ wt,
    const float* __restrict__ b1, const float* __restrict__ g1,
    const float* __restrict__ be1,
    const float* __restrict__ b2, const float* __restrict__ lng,
    const float* __restrict__ lnb,
    const float* __restrict__ b1p, const float* __restrict__ g1p,
    const float* __restrict__ be1p,
    const float* __restrict__ b2p, const float* __restrict__ lnpg,
    const float* __restrict__ lnpb,
    const float* __restrict__ x, float* __restrict__ out) {
  __shared__ ushort_t lds[64 * 128];   // 16 KB
  const int lane = threadIdx.x & 63;
  const int wv   = threadIdx.x >> 6;   // 0..1
  const int g    = lane >> 4;
  const int c0   = lane & 15;
  const int rb   = wv * 32;            // local row base
  const int bid  = blockIdx.x;

  f32x4 acc[2][8];

  if (bid < HB) {
    // =============== h-branch: 64 nodes ===============
    const int m0 = bid * 64;
    const ushort_t* W1t = wt;
    const ushort_t* W2t = wt + 24576;

    // ---- GEMM1: h0[.,192] @ W1 ----
    bf16x8 a0[6], a1[6];
#pragma unroll
    for (int ks = 0; ks < 6; ++ks) {
      a0[ks] = *(const bf16x8*)(h0 + (size_t)(m0 + rb + c0) * DD + ks * 32 + g * 8);
      a1[ks] = *(const bf16x8*)(h0 + (size_t)(m0 + rb + 16 + c0) * DD + ks * 32 + g * 8);
    }
#pragma unroll
    for (int mt = 0; mt < 2; ++mt)
#pragma unroll
      for (int nt = 0; nt < 8; ++nt) acc[mt][nt] = (f32x4){0.f, 0.f, 0.f, 0.f};
#pragma unroll
    for (int ks = 0; ks < 6; ++ks)
#pragma unroll
      for (int nt = 0; nt < 8; ++nt) {
        bf16x8 b = *(const bf16x8*)(W1t + (nt * 16 + c0) * DD + ks * 32 + g * 8);
        acc[0][nt] = MFMA16(a0[ks], b, acc[0][nt], 0, 0, 0);
        acc[1][nt] = MFMA16(a1[ks], b, acc[1][nt], 0, 0, 0);
      }
    ln_epi(acc, b1, g1, be1, c0);
    lds_write_acc(lds, acc, rb, g, c0);

    // ---- GEMM2: h1 @ W2 -> LN -> relu -> +x ----
#pragma unroll
    for (int mt = 0; mt < 2; ++mt)
#pragma unroll
      for (int nt = 0; nt < 8; ++nt) acc[mt][nt] = (f32x4){0.f, 0.f, 0.f, 0.f};
#pragma unroll
    for (int ks = 0; ks < 4; ++ks)
#pragma unroll
      for (int mt = 0; mt < 2; ++mt) {
        int lr   = rb + mt * 16 + c0;
        int byte = lr * 256 + (((ks * 32 + g * 8) * 2) ^ ((lr & 7) << 4));
        bf16x8 a = *(const bf16x8*)((const char*)lds + byte);
#pragma unroll
        for (int nt = 0; nt < 8; ++nt) {
          bf16x8 b = *(const bf16x8*)(W2t + (nt * 16 + c0) * EMBD + ks * 32 + g * 8);
          acc[mt][nt] = MFMA16(a, b, acc[mt][nt], 0, 0, 0);
        }
      }
    ln_epi(acc, b2, lng, lnb, c0);
#pragma unroll
    for (int mt = 0; mt < 2; ++mt)
#pragma unroll
      for (int nt = 0; nt < 8; ++nt)
#pragma unroll
        for (int r = 0; r < 4; ++r) {
          int node = m0 + rb + mt * 16 + g * 4 + r;
          int col  = nt * 16 + c0;
          if (node < NN)
            out[(size_t)node * EMBD + col] =
                acc[mt][nt][r] + x[(size_t)node * IND + col];
        }
  } else {
    // =============== p-branch: 64 nodes ===============
    const int m0 = (bid - HB) * 64;
    const ushort_t* W1pt = wt + 24576 + 16384;
    const ushort_t* W2pt = wt + 24576 + 16384 + 8192;

    // ---- GEMM1p: p0[.,64] @ W1p ----
    bf16x8 a0[2], a1[2];
#pragma unroll
    for (int ks = 0; ks < 2; ++ks) {
      a0[ks] = *(const bf16x8*)(p0 + (size_t)(m0 + rb + c0) * POSD + ks * 32 + g * 8);
      a1[ks] = *(const bf16x8*)(p0 + (size_t)(m0 + rb + 16 + c0) * POSD + ks * 32 + g * 8);
    }
#pragma unroll
    for (int mt = 0; mt < 2; ++mt)
#pragma unroll
      for (int nt = 0; nt < 8; ++nt) acc[mt][nt] = (f32x4){0.f, 0.f, 0.f, 0.f};
#pragma unroll
    for (int ks = 0; ks < 2; ++ks)
#pragma unroll
      for (int nt = 0; nt < 8; ++nt) {
        bf16x8 b = *(const bf16x8*)(W1pt + (nt * 16 + c0) * POSD + ks * 32 + g * 8);
        acc[0][nt] = MFMA16(a0[ks], b, acc[0][nt], 0, 0, 0);
        acc[1][nt] = MFMA16(a1[ks], b, acc[1][nt], 0, 0, 0);
      }
    ln_epi(acc, b1p, g1p, be1p, c0);
    lds_write_acc(lds, acc, rb, g, c0);

    // ---- GEMM2p: p1 @ W2p -> LN -> relu ----
#pragma unroll
    for (int mt = 0; mt < 2; ++mt)
#pragma unroll
      for (int nt = 0; nt < 8; ++nt) acc[mt][nt] = (f32x4){0.f, 0.f, 0.f, 0.f};
#pragma unroll
    for (int ks = 0; ks < 4; ++ks)
#pragma unroll
      for (int mt = 0; mt < 2; ++mt) {
        int lr   = rb + mt * 16 + c0;
        int byte = lr * 256 + (((ks * 32 + g * 8) * 2) ^ ((lr & 7) << 4));
        bf16x8 a = *(const bf16x8*)((const char*)lds + byte);
#pragma unroll
        for (int nt = 0; nt < 8; ++nt) {
          bf16x8 b = *(const bf16x8*)(W2pt + (nt * 16 + c0) * EMBD + ks * 32 + g * 8);
          acc[mt][nt] = MFMA16(a, b, acc[mt][nt], 0, 0, 0);
        }
      }
    ln_epi(acc, b2p, lnpg, lnpb, c0);
#pragma unroll
    for (int mt = 0; mt < 2; ++mt)
#pragma unroll
      for (int nt = 0; nt < 8; ++nt)
#pragma unroll
        for (int r = 0; r < 4; ++r) {
          int node = m0 + rb + mt * 16 + g * 4 + r;
          int col  = nt * 16 + c0;
          if (node < NN)
            out[(size_t)NN * EMBD + (size_t)node * EMBD + col] = acc[mt][nt][r];
        }
  }
}

extern "C" void kernel_launch(void* const* d_in, const int* in_sizes, int n_in,
                              void* d_out, int out_size, void* d_ws, size_t ws_size,
                              hipStream_t stream) {
  const float* x    = (const float*)d_in[0];
  const float* pos  = (const float*)d_in[1];
  const int*   ei   = (const int*)d_in[2];
  const float* eps  = (const float*)d_in[3];
  const float* W1   = (const float*)d_in[4];
  const float* b1   = (const float*)d_in[5];
  const float* g1   = (const float*)d_in[6];
  const float* be1  = (const float*)d_in[7];
  const float* W2   = (const float*)d_in[8];
  const float* b2   = (const float*)d_in[9];
  const float* lng  = (const float*)d_in[10];
  const float* lnb  = (const float*)d_in[11];
  const float* epsp = (const float*)d_in[12];
  const float* W1p  = (const float*)d_in[13];
  const float* b1p  = (const float*)d_in[14];
  const float* g1p  = (const float*)d_in[15];
  const float* be1p = (const float*)d_in[16];
  const float* W2p  = (const float*)d_in[17];
  const float* b2p  = (const float*)d_in[18];
  const float* lnpg = (const float*)d_in[19];
  const float* lnpb = (const float*)d_in[20];

  char* ws = (char*)d_ws;
  int*      cnt = (int*)ws;                                  // 200,000 B
  int*      csr = (int*)(ws + 200000);                       // 6,400,000 B
  ushort_t* h0  = (ushort_t*)(ws + 6600000);                 // NPAD*192*2
  ushort_t* p0  = (ushort_t*)(ws + 25818432);                // NPAD*64*2
  ushort_t* wt  = (ushort_t*)(ws + 32224576);                // 131,072 B
  float*    out = (float*)d_out;

  hipMemsetAsync(cnt, 0, (size_t)NN * sizeof(int), stream);
  fill_k<<<(EE + 255) / 256, 256, 0, stream>>>(ei, cnt, csr);
  wconv_k<<<256, 256, 0, stream>>>(W1, W2, W1p, W2p, wt);
  gather_k<<<NPAD / 4, 256, 0, stream>>>(x, pos, cnt, csr, eps, epsp, h0, p0);
  mlp_k<<<2 * HB, 128, 0, stream>>>(
      h0, p0, wt, b1, g1, be1, b2, lng, lnb,
      b1p, g1p, be1p, b2p, lnpg, lnpb, x, out);
}

// Round 5
// 126.246 us; speedup vs baseline: 11.1101x; 1.2162x over previous
//
#include <hip/hip_runtime.h>

#define NN    50000
#define NPAD  50048       // 391 * 128
#define HB    391         // h-branch blocks (128 rows each)
#define EE    400000
#define IND   128
#define POSD  64
#define DD    192
#define EMBD  128
#define LNEPS 1e-5f
#define CAP   32

typedef __attribute__((ext_vector_type(8))) short bf16x8;
typedef __attribute__((ext_vector_type(4))) float f32x4;
typedef unsigned short ushort_t;

#define MFMA16 __builtin_amdgcn_mfma_f32_16x16x32_bf16

__device__ inline ushort_t f2bf(float f) {
  union { float f; unsigned u; } v; v.f = f;
  unsigned r = (v.u + 0x7FFFu + ((v.u >> 16) & 1u)) >> 16;
  return (ushort_t)r;
}

// ---------------------------------------------------------------------------
// Kernel 1: CSR bucket fill (int atomics only)
// ---------------------------------------------------------------------------
__global__ __launch_bounds__(256) void fill_k(
    const int* __restrict__ ei, int* __restrict__ cnt, int* __restrict__ csr) {
  int e = blockIdx.x * 256 + threadIdx.x;
  if (e >= EE) return;
  int src = ei[e];
  int dst = ei[EE + e];
  int idx = atomicAdd(&cnt[dst], 1);
  if (idx < CAP) csr[(size_t)dst * CAP + idx] = src;
}

// ---------------------------------------------------------------------------
// Kernel 2: weights -> bf16, transposed to [col][k]
// wt (ushort units): W1t@0 [128][192] | W2t@24576 [128][128]
//                  | W1pt@40960 [128][64] | W2pt@49152 [128][128]
// ---------------------------------------------------------------------------
__global__ __launch_bounds__(256) void wconv_k(
    const float* __restrict__ W1, const float* __restrict__ W2,
    const float* __restrict__ W1p, const float* __restrict__ W2p,
    ushort_t* __restrict__ wt) {
  int tid = blockIdx.x * 256 + threadIdx.x;   // 65536 total
  if (tid < 24576) {                                   // W1t
    int c = tid / 192, k = tid % 192;
    wt[tid] = f2bf(W1[k * EMBD + c]);
  } else if (tid < 24576 + 16384) {                    // W2t
    int t = tid - 24576; int c = t / 128, k = t % 128;
    wt[tid] = f2bf(W2[k * EMBD + c]);
  } else if (tid < 24576 + 16384 + 8192) {             // W1pt
    int t = tid - 24576 - 16384; int c = t / 64, k = t % 64;
    wt[tid] = f2bf(W1p[k * EMBD + c]);
  } else {                                             // W2pt
    int t = tid - 24576 - 16384 - 8192; int c = t / 128, k = t % 128;
    wt[tid] = f2bf(W2p[k * EMBD + c]);
  }
}

// ---------------------------------------------------------------------------
// Kernel 3: gather. One wave per node; covers NPAD (pad rows -> zeros).
// ---------------------------------------------------------------------------
__global__ __launch_bounds__(256) void gather_k(
    const float* __restrict__ x, const float* __restrict__ pos,
    const int* __restrict__ cnt, const int* __restrict__ csr,
    const float* __restrict__ epsv, const float* __restrict__ epspv,
    ushort_t* __restrict__ h0, ushort_t* __restrict__ p0) {
  const int lane = threadIdx.x & 63;
  const int wv   = threadIdx.x >> 6;
  const int n    = blockIdx.x * 4 + wv;
  if (n >= NPAD) return;

  float a0 = 0.f, a1 = 0.f, a2 = 0.f;
  float xs0 = 0.f, xs1 = 0.f, ps = 0.f;

  if (n < NN) {
    int deg = cnt[n]; if (deg > CAP) deg = CAP;
    const int* row = csr + (size_t)n * CAP;
    int idx = (lane < deg) ? row[lane] : 0;
    int t = 0;
    for (; t + 2 <= deg; t += 2) {
      int s1 = __shfl(idx, t);
      int s2 = __shfl(idx, t + 1);
      float u0 = x[(size_t)s1 * IND + lane];
      float u1 = x[(size_t)s1 * IND + 64 + lane];
      float u2 = pos[(size_t)s1 * POSD + lane];
      float v0 = x[(size_t)s2 * IND + lane];
      float v1 = x[(size_t)s2 * IND + 64 + lane];
      float v2 = pos[(size_t)s2 * POSD + lane];
      a0 += u0 + v0; a1 += u1 + v1; a2 += u2 + v2;
    }
    if (t < deg) {
      int s1 = __shfl(idx, t);
      a0 += x[(size_t)s1 * IND + lane];
      a1 += x[(size_t)s1 * IND + 64 + lane];
      a2 += pos[(size_t)s1 * POSD + lane];
    }
    xs0 = x[(size_t)n * IND + lane];
    xs1 = x[(size_t)n * IND + 64 + lane];
    ps  = pos[(size_t)n * POSD + lane];
  }

  float e1  = 1.0f + epsv[0];
  float ep1 = 1.0f + epspv[0];
  h0[(size_t)n * DD + lane]       = f2bf(fmaf(e1, xs0, a0));
  h0[(size_t)n * DD + 64 + lane]  = f2bf(fmaf(e1, xs1, a1));
  h0[(size_t)n * DD + 128 + lane] = f2bf(fmaf(e1, ps,  a2));
  p0[(size_t)n * POSD + lane]     = f2bf(fmaf(ep1, ps, a2));
}

// ---------------------------------------------------------------------------
// LN+bias+relu on 2x8 f32x4 acc. C layout: col=lane&15, row=(lane>>4)*4+reg.
// ---------------------------------------------------------------------------
__device__ inline void ln_epi(f32x4 (&acc)[2][8],
                              const float* __restrict__ bias,
                              const float* __restrict__ gam,
                              const float* __restrict__ bet, int c0) {
  float bv[8], gv[8], bev[8];
#pragma unroll
  for (int nt = 0; nt < 8; ++nt) {
    bv[nt]  = bias[nt * 16 + c0];
    gv[nt]  = gam[nt * 16 + c0];
    bev[nt] = bet[nt * 16 + c0];
  }
#pragma unroll
  for (int mt = 0; mt < 2; ++mt) {
#pragma unroll
    for (int r = 0; r < 4; ++r) {
      float s = 0.f, sq = 0.f;
#pragma unroll
      for (int nt = 0; nt < 8; ++nt) {
        float v = acc[mt][nt][r] + bv[nt];
        acc[mt][nt][r] = v;
        s += v; sq += v * v;
      }
#pragma unroll
      for (int off = 1; off < 16; off <<= 1) {
        s  += __shfl_xor(s, off);
        sq += __shfl_xor(sq, off);
      }
      float mean = s * (1.0f / 128.0f);
      float var  = sq * (1.0f / 128.0f) - mean * mean;
      float rstd = rsqrtf(var + LNEPS);
#pragma unroll
      for (int nt = 0; nt < 8; ++nt) {
        acc[mt][nt][r] =
            fmaxf(fmaf((acc[mt][nt][r] - mean) * rstd, gv[nt], bev[nt]), 0.f);
      }
    }
  }
}

// write acc (post-LN) as bf16 into wave-private act slab (32 rows), swizzled
__device__ inline void act_write(char* act, f32x4 (&acc)[2][8], int g, int c0) {
#pragma unroll
  for (int mt = 0; mt < 2; ++mt)
#pragma unroll
    for (int nt = 0; nt < 8; ++nt)
#pragma unroll
      for (int r = 0; r < 4; ++r) {
        int lr   = mt * 16 + g * 4 + r;
        int byte = lr * 256 + (((nt * 16 + c0) * 2) ^ ((lr & 7) << 4));
        *(ushort_t*)(act + byte) = f2bf(acc[mt][nt][r]);
      }
}

// stage a [rows][rowbytes] bf16 weight panel global->LDS with XOR swizzle
__device__ inline void stage_w(const ushort_t* __restrict__ src, char* dst,
                               int rowbytes, int chunks, int tid) {
  int cpr = rowbytes >> 4;   // 16B chunks per row
  for (int i = tid; i < chunks; i += 256) {
    int row  = i / cpr;
    int colb = (i - row * cpr) << 4;
    *(bf16x8*)(dst + row * rowbytes + (colb ^ ((row & 7) << 4))) =
        *(const bf16x8*)(src + (size_t)i * 8);
  }
}

// ---------------------------------------------------------------------------
// Kernel 4: MFMA MLP, weights staged in LDS.
// 256 thr (4 waves), 128 rows/block. Blocks [0,HB): h; [HB,2HB): p.
// LDS: 48KB weight buffer + 4x8KB act slabs = 80KB -> 2 blocks/CU.
// ---------------------------------------------------------------------------
__global__ __launch_bounds__(256) void mlp_k(
    const ushort_t* __restrict__ h0, const ushort_t* __restrict__ p0,
    const ushort_t* __restrict__ wt,
    const float* __restrict__ b1, const float* __restrict__ g1,
    const float* __restrict__ be1,
    const float* __restrict__ b2, const float* __restrict__ lng,
    const float* __restrict__ lnb,
    const float* __restrict__ b1p, const float* __restrict__ g1p,
    const float* __restrict__ be1p,
    const float* __restrict__ b2p, const float* __restrict__ lnpg,
    const float* __restrict__ lnpb,
    const float* __restrict__ x, float* __restrict__ out) {
  __shared__ __align__(16) char smem[81920];
  const int tid  = threadIdx.x;
  const int lane = tid & 63;
  const int wv   = tid >> 6;           // 0..3
  const int g    = lane >> 4;
  const int c0   = lane & 15;
  const int bid  = blockIdx.x;
  char* act = smem + 49152 + wv * 8192;   // wave-private 32x128 bf16 slab

  f32x4 acc[2][8];

  if (bid < HB) {
    // =============== h-branch: 128 nodes ===============
    const int m0 = bid * 128;
    stage_w(wt, smem, 384, 3072, tid);          // W1t [128][192]
    // preload A-fragments while staging is in flight
    bf16x8 a0[6], a1[6];
    const size_t r0 = (size_t)(m0 + wv * 32 + c0) * DD;
    const size_t r1 = r0 + (size_t)16 * DD;
#pragma unroll
    for (int ks = 0; ks < 6; ++ks) {
      a0[ks] = *(const bf16x8*)(h0 + r0 + ks * 32 + g * 8);
      a1[ks] = *(const bf16x8*)(h0 + r1 + ks * 32 + g * 8);
    }
    __syncthreads();

    // ---- GEMM1: B from LDS ----
#pragma unroll
    for (int mt = 0; mt < 2; ++mt)
#pragma unroll
      for (int nt = 0; nt < 8; ++nt) acc[mt][nt] = (f32x4){0.f, 0.f, 0.f, 0.f};
#pragma unroll
    for (int ks = 0; ks < 6; ++ks)
#pragma unroll
      for (int nt = 0; nt < 8; ++nt) {
        int wrow = nt * 16 + c0;
        bf16x8 b = *(const bf16x8*)(smem + wrow * 384 +
                                    ((ks * 64 + g * 16) ^ ((wrow & 7) << 4)));
        acc[0][nt] = MFMA16(a0[ks], b, acc[0][nt], 0, 0, 0);
        acc[1][nt] = MFMA16(a1[ks], b, acc[1][nt], 0, 0, 0);
      }
    ln_epi(acc, b1, g1, be1, c0);
    act_write(act, acc, g, c0);
    __syncthreads();                            // all GEMM1 LDS reads done
    stage_w(wt + 24576, smem, 256, 2048, tid);  // W2t [128][128]
    __syncthreads();

    // ---- GEMM2: A from act slab, B from LDS; +residual ----
#pragma unroll
    for (int mt = 0; mt < 2; ++mt)
#pragma unroll
      for (int nt = 0; nt < 8; ++nt) acc[mt][nt] = (f32x4){0.f, 0.f, 0.f, 0.f};
#pragma unroll
    for (int ks = 0; ks < 4; ++ks) {
      bf16x8 am[2];
#pragma unroll
      for (int mt = 0; mt < 2; ++mt) {
        int lr = mt * 16 + c0;
        am[mt] = *(const bf16x8*)(act + lr * 256 +
                                  (((ks * 32 + g * 8) * 2) ^ ((lr & 7) << 4)));
      }
#pragma unroll
      for (int nt = 0; nt < 8; ++nt) {
        int wrow = nt * 16 + c0;
        bf16x8 b = *(const bf16x8*)(smem + wrow * 256 +
                                    ((ks * 64 + g * 16) ^ ((wrow & 7) << 4)));
        acc[0][nt] = MFMA16(am[0], b, acc[0][nt], 0, 0, 0);
        acc[1][nt] = MFMA16(am[1], b, acc[1][nt], 0, 0, 0);
      }
    }
    ln_epi(acc, b2, lng, lnb, c0);
#pragma unroll
    for (int mt = 0; mt < 2; ++mt)
#pragma unroll
      for (int nt = 0; nt < 8; ++nt)
#pragma unroll
        for (int r = 0; r < 4; ++r) {
          int node = m0 + wv * 32 + mt * 16 + g * 4 + r;
          int col  = nt * 16 + c0;
          if (node < NN)
            out[(size_t)node * EMBD + col] =
                acc[mt][nt][r] + x[(size_t)node * IND + col];
        }
  } else {
    // =============== p-branch: 128 nodes ===============
    const int m0 = (bid - HB) * 128;
    stage_w(wt + 40960, smem, 128, 1024, tid);          // W1pt [128][64]
    stage_w(wt + 49152, smem + 16384, 256, 2048, tid);  // W2pt [128][128]
    bf16x8 a0[2], a1[2];
    const size_t r0 = (size_t)(m0 + wv * 32 + c0) * POSD;
    const size_t r1 = r0 + (size_t)16 * POSD;
#pragma unroll
    for (int ks = 0; ks < 2; ++ks) {
      a0[ks] = *(const bf16x8*)(p0 + r0 + ks * 32 + g * 8);
      a1[ks] = *(const bf16x8*)(p0 + r1 + ks * 32 + g * 8);
    }
    __syncthreads();

    // ---- GEMM1p ----
#pragma unroll
    for (int mt = 0; mt < 2; ++mt)
#pragma unroll
      for (int nt = 0; nt < 8; ++nt) acc[mt][nt] = (f32x4){0.f, 0.f, 0.f, 0.f};
#pragma unroll
    for (int ks = 0; ks < 2; ++ks)
#pragma unroll
      for (int nt = 0; nt < 8; ++nt) {
        int wrow = nt * 16 + c0;
        bf16x8 b = *(const bf16x8*)(smem + wrow * 128 +
                                    ((ks * 64 + g * 16) ^ ((wrow & 7) << 4)));
        acc[0][nt] = MFMA16(a0[ks], b, acc[0][nt], 0, 0, 0);
        acc[1][nt] = MFMA16(a1[ks], b, acc[1][nt], 0, 0, 0);
      }
    ln_epi(acc, b1p, g1p, be1p, c0);
    act_write(act, acc, g, c0);

    // ---- GEMM2p (wave-private act; W2pt already staged; no sync needed) ----
#pragma unroll
    for (int mt = 0; mt < 2; ++mt)
#pragma unroll
      for (int nt = 0; nt < 8; ++nt) acc[mt][nt] = (f32x4){0.f, 0.f, 0.f, 0.f};
#pragma unroll
    for (int ks = 0; ks < 4; ++ks) {
      bf16x8 am[2];
#pragma unroll
      for (int mt = 0; mt < 2; ++mt) {
        int lr = mt * 16 + c0;
        am[mt] = *(const bf16x8*)(act + lr * 256 +
                                  (((ks * 32 + g * 8) * 2) ^ ((lr & 7) << 4)));
      }
#pragma unroll
      for (int nt = 0; nt < 8; ++nt) {
        int wrow = nt * 16 + c0;
        bf16x8 b = *(const bf16x8*)(smem + 16384 + wrow * 256 +
                                    ((ks * 64 + g * 16) ^ ((wrow & 7) << 4)));
        acc[0][nt] = MFMA16(am[0], b, acc[0][nt], 0, 0, 0);
        acc[1][nt] = MFMA16(am[1], b, acc[1][nt], 0, 0, 0);
      }
    }
    ln_epi(acc, b2p, lnpg, lnpb, c0);
#pragma unroll
    for (int mt = 0; mt < 2; ++mt)
#pragma unroll
      for (int nt = 0; nt < 8; ++nt)
#pragma unroll
        for (int r = 0; r < 4; ++r) {
          int node = m0 + wv * 32 + mt * 16 + g * 4 + r;
          int col  = nt * 16 + c0;
          if (node < NN)
            out[(size_t)NN * EMBD + (size_t)node * EMBD + col] = acc[mt][nt][r];
        }
  }
}

extern "C" void kernel_launch(void* const* d_in, const int* in_sizes, int n_in,
                              void* d_out, int out_size, void* d_ws, size_t ws_size,
                              hipStream_t stream) {
  const float* x    = (const float*)d_in[0];
  const float* pos  = (const float*)d_in[1];
  const int*   ei   = (const int*)d_in[2];
  const float* eps  = (const float*)d_in[3];
  const float* W1   = (const float*)d_in[4];
  const float* b1   = (const float*)d_in[5];
  const float* g1   = (const float*)d_in[6];
  const float* be1  = (const float*)d_in[7];
  const float* W2   = (const float*)d_in[8];
  const float* b2   = (const float*)d_in[9];
  const float* lng  = (const float*)d_in[10];
  const float* lnb  = (const float*)d_in[11];
  const float* epsp = (const float*)d_in[12];
  const float* W1p  = (const float*)d_in[13];
  const float* b1p  = (const float*)d_in[14];
  const float* g1p  = (const float*)d_in[15];
  const float* be1p = (const float*)d_in[16];
  const float* W2p  = (const float*)d_in[17];
  const float* b2p  = (const float*)d_in[18];
  const float* lnpg = (const float*)d_in[19];
  const float* lnpb = (const float*)d_in[20];

  char* ws = (char*)d_ws;
  int*      cnt = (int*)ws;                                  // 200,000 B
  int*      csr = (int*)(ws + 200000);                       // 6,400,000 B
  ushort_t* h0  = (ushort_t*)(ws + 6600000);                 // NPAD*192*2
  ushort_t* p0  = (ushort_t*)(ws + 25818432);                // NPAD*64*2
  ushort_t* wt  = (ushort_t*)(ws + 32224576);                // 131,072 B
  float*    out = (float*)d_out;

  hipMemsetAsync(cnt, 0, (size_t)NN * sizeof(int), stream);
  fill_k<<<(EE + 255) / 256, 256, 0, stream>>>(ei, cnt, csr);
  wconv_k<<<256, 256, 0, stream>>>(W1, W2, W1p, W2p, wt);
  gather_k<<<NPAD / 4, 256, 0, stream>>>(x, pos, cnt, csr, eps, epsp, h0, p0);
  mlp_k<<<2 * HB, 256, 0, stream>>>(
      h0, p0, wt, b1, g1, be1, b2, lng, lnb,
      b1p, g1p, be1p, b2p, lnpg, lnpb, x, out);
}